// Round 2
// baseline (213.795 us; speedup 1.0000x reference)
//
#include <hip/hip_runtime.h>

#define THREADS 256
#define TPB 128            // tokens per block
#define C_DIM 64
#define K_CODES 1024
#define CHUNK_K 64
#define N_CHUNKS (K_CODES / CHUNK_K)
#define CB_PAD 68          // 64 + 4: keeps 16B alignment for b128 reads

#define QUANT_OFF 0
#define LOSS_OFF  4194304
#define IDX_OFF   4194306

__global__ __launch_bounds__(THREADS, 2) void vq_main(
    const float* __restrict__ x,     // [64][64][32][32]
    const float* __restrict__ cb,    // [1024][64]
    float* __restrict__ out,
    double* __restrict__ ws_sum)
{
    __shared__ float xt_s[C_DIM][TPB];        // 32 KB  token tile, c-major
    __shared__ float cb_s[C_DIM][CB_PAD];     // 17.4 KB codebook chunk, c-major
    __shared__ float cbsq_all[K_CODES];       // 4 KB
    __shared__ float red_v[8][TPB];           // 4 KB
    __shared__ int   red_i[8][TPB];           // 4 KB
    __shared__ int   kidx_s[TPB];

    const int tid  = threadIdx.x;
    const int blk  = blockIdx.x;
    const int tok0 = blk * TPB;
    const int b_img = tok0 >> 10;             // token/1024 (HW=1024)
    const int hw0   = tok0 & 1023;

    // ---- precompute codebook squared norms (L2-resident reads) ----
    {
        #pragma unroll
        for (int r = 0; r < 4; ++r) {
            int k = tid + r * THREADS;
            const float4* row = reinterpret_cast<const float4*>(cb + k * C_DIM);
            float s = 0.f;
            #pragma unroll
            for (int j = 0; j < 16; ++j) {
                float4 v = row[j];
                s = fmaf(v.x, v.x, s); s = fmaf(v.y, v.y, s);
                s = fmaf(v.z, v.z, s); s = fmaf(v.w, v.w, s);
            }
            cbsq_all[k] = s;
        }
    }

    // ---- stage x tile transposed: xt_s[c][i] (coalesced 256B rows) ----
    {
        const int i  = tid & (TPB - 1);
        const int c0 = tid >> 7;              // 0..1
        #pragma unroll
        for (int j = 0; j < 32; ++j) {
            int c = c0 + 2 * j;
            xt_s[c][i] = x[((b_img * C_DIM + c) << 10) + hw0 + i];
        }
    }

    const int tl = tid & 31;                  // token lane: tokens tl*4 .. tl*4+3
    const int kg = tid >> 5;                  // k-group 0..7: 8 codes per chunk

    float minv[4];
    int   mini[4];
    #pragma unroll
    for (int m = 0; m < 4; ++m) { minv[m] = 3.4e38f; mini[m] = 0; }

    for (int ch = 0; ch < N_CHUNKS; ++ch) {
        __syncthreads();                      // protect cb_s from previous pass
        // stage 64-code chunk transposed: cb_s[c][kl] (coalesced global rows)
        for (int t = tid; t < CHUNK_K * C_DIM; t += THREADS) {
            int kl = t >> 6;
            int c  = t & 63;
            cb_s[c][kl] = cb[(ch * CHUNK_K + kl) * C_DIM + c];
        }
        __syncthreads();

        float dot[4][8];
        #pragma unroll
        for (int m = 0; m < 4; ++m)
            #pragma unroll
            for (int k = 0; k < 8; ++k) dot[m][k] = 0.f;

        #pragma unroll 4
        for (int c = 0; c < C_DIM; ++c) {
            float4 xv  = *reinterpret_cast<const float4*>(&xt_s[c][tl * 4]);
            float4 cv0 = *reinterpret_cast<const float4*>(&cb_s[c][kg * 8]);     // wave-broadcast
            float4 cv1 = *reinterpret_cast<const float4*>(&cb_s[c][kg * 8 + 4]); // wave-broadcast
            float xa[4] = {xv.x, xv.y, xv.z, xv.w};
            float ca[8] = {cv0.x, cv0.y, cv0.z, cv0.w, cv1.x, cv1.y, cv1.z, cv1.w};
            #pragma unroll
            for (int m = 0; m < 4; ++m)
                #pragma unroll
                for (int k = 0; k < 8; ++k)
                    dot[m][k] = fmaf(xa[m], ca[k], dot[m][k]);
        }

        const int codebase = ch * CHUNK_K + kg * 8;
        #pragma unroll
        for (int k = 0; k < 8; ++k) {
            float csq = cbsq_all[codebase + k];
            #pragma unroll
            for (int m = 0; m < 4; ++m) {
                float sc = fmaf(-2.f, dot[m][k], csq);
                // strict < keeps first (lowest-k) min within this thread
                if (sc < minv[m]) { minv[m] = sc; mini[m] = codebase + k; }
            }
        }
    }

    // ---- cross-kgroup argmin reduce (lexicographic: value, then index) ----
    #pragma unroll
    for (int m = 0; m < 4; ++m) {
        red_v[kg][tl * 4 + m] = minv[m];
        red_i[kg][tl * 4 + m] = mini[m];
    }
    __syncthreads();
    if (tid < TPB) {
        float bv = red_v[0][tid];
        int   bi = red_i[0][tid];
        #pragma unroll
        for (int g = 1; g < 8; ++g) {
            float v  = red_v[g][tid];
            int   ii = red_i[g][tid];
            if (v < bv || (v == bv && ii < bi)) { bv = v; bi = ii; }
        }
        kidx_s[tid] = bi;
        out[IDX_OFF + tok0 + tid] = (float)bi;   // argmin index, float per output dtype
    }
    __syncthreads();

    // ---- epilogue: quant write (STE form) + loss partial ----
    {
        const int i  = tid & (TPB - 1);
        const int c0 = tid >> 7;                  // 0..1
        const int kk = kidx_s[i];
        const float* crow = cb + kk * C_DIM;      // L2-resident gather
        float lsum = 0.f;
        #pragma unroll
        for (int j = 0; j < 32; ++j) {
            int c = c0 * 32 + j;
            float q  = crow[c];
            float xv = xt_s[c][i];
            float d  = q - xv;                    // (quant - xt)
            lsum = fmaf(d, d, lsum);
            // STE: xt + sg(quant - xt)  (== quant in fp32, kept in reference form)
            out[QUANT_OFF + ((b_img * C_DIM + c) << 10) + hw0 + i] = xv + d;
        }
        // wave reduce then one atomic per wave
        #pragma unroll
        for (int off = 32; off > 0; off >>= 1)
            lsum += __shfl_down(lsum, off, 64);
        if ((tid & 63) == 0)
            atomicAdd(ws_sum, (double)lsum);
    }
}

__global__ void vq_finalize(const double* __restrict__ ws_sum,
                            float* __restrict__ out)
{
    float m = (float)(ws_sum[0] / 4194304.0);
    out[LOSS_OFF]     = m;   // loss_embed
    out[LOSS_OFF + 1] = m;   // loss_commitment (identical forward value)
}

extern "C" void kernel_launch(void* const* d_in, const int* in_sizes, int n_in,
                              void* d_out, int out_size, void* d_ws, size_t ws_size,
                              hipStream_t stream) {
    const float* x  = (const float*)d_in[0];
    const float* cb = (const float*)d_in[1];
    float* out      = (float*)d_out;
    double* ws_sum  = (double*)d_ws;

    hipMemsetAsync(d_ws, 0, sizeof(double), stream);
    vq_main<<<512, THREADS, 0, stream>>>(x, cb, out, ws_sum);
    vq_finalize<<<1, 1, 0, stream>>>(ws_sum, out);
}

// Round 5
// 147.452 us; speedup vs baseline: 1.4499x; 1.4499x over previous
//
#include <hip/hip_runtime.h>

#define THREADS 256
#define M_BLOCK 128
#define C_DIM 64
#define K_CODES 1024
#define N_CHUNK 64
#define N_CHUNKS 16

#define QUANT_OFF 0
#define LOSS_OFF  4194304
#define IDX_OFF   4194306

// ws layout (bytes): [0..8) double loss-sum; [64..4160) 0.5*|cb|^2 (1024 f32);
// [8192..401408) B-stream: 16 chunks x 24 segs x 1024 B (bf16, negated splits)
#define WS_CBSQH_F 16
#define WS_STREAM_B 8192
#define CHUNK_BYTES 24576
#define SEG_BYTES 1024
#define WS_NEEDED (WS_STREAM_B + N_CHUNKS * CHUNK_BYTES)

typedef float floatx16 __attribute__((ext_vector_type(16)));
typedef short bf16x8  __attribute__((ext_vector_type(8)));

typedef __attribute__((address_space(1))) const void gv_t;
typedef __attribute__((address_space(3))) void lv_t;

static __device__ inline unsigned short f2bf(float v) {
    unsigned int u = __float_as_uint(v);
    unsigned int r = (u + 0x7FFF + ((u >> 16) & 1)) >> 16;   // RNE
    return (unsigned short)r;
}
static __device__ inline float bf2f(unsigned short b) {
    return __uint_as_float(((unsigned int)b) << 16);
}

// ---------------- prep: cb -> negated bf16 split stream + 0.5*|cb|^2 ----------------
__global__ void vq_prep(const float* __restrict__ cb, float* __restrict__ ws)
{
    const int tid = threadIdx.x;
    if (blockIdx.x >= 96) {                       // blocks 96..99: cb_sq/2
        int code = (blockIdx.x - 96) * 256 + tid;
        const float4* row = reinterpret_cast<const float4*>(cb + code * C_DIM);
        float s = 0.f;
        #pragma unroll
        for (int j = 0; j < 16; ++j) {
            float4 v = row[j];
            s = fmaf(v.x, v.x, s); s = fmaf(v.y, v.y, s);
            s = fmaf(v.z, v.z, s); s = fmaf(v.w, v.w, s);
        }
        ws[WS_CBSQH_F + code] = 0.5f * s;
        return;
    }
    // blocks 0..95: stream. gid in [0, 24576): (chunk, seg, lane)
    int gid   = blockIdx.x * 256 + tid;
    int chunk = gid / 1536;
    int rem   = gid - chunk * 1536;
    int seg   = rem >> 6;                         // 0..23 = wc*12 + tb*4 + s4
    int lane  = rem & 63;
    int wc = seg / 12;
    int tb = (seg % 12) >> 2;
    int s4 = seg & 3;
    int code = chunk * N_CHUNK + wc * 32 + (lane & 31);
    int c0   = s4 * 16 + ((lane >> 5) << 3);
    const float* src = cb + code * C_DIM + c0;
    unsigned short us[8];
    #pragma unroll
    for (int j = 0; j < 8; ++j) {
        float v  = src[j];
        float h  = bf2f(f2bf(v));
        float r1 = v - h;                 // exact
        float m  = bf2f(f2bf(r1));
        float r2 = r1 - m;                // exact
        float sel = (tb == 0) ? h : (tb == 1) ? m : r2;
        us[j] = f2bf(-sel);               // negate: MFMA accumulates -dot
    }
    uint4 o;
    o.x = (unsigned)us[0] | ((unsigned)us[1] << 16);
    o.y = (unsigned)us[2] | ((unsigned)us[3] << 16);
    o.z = (unsigned)us[4] | ((unsigned)us[5] << 16);
    o.w = (unsigned)us[6] | ((unsigned)us[7] << 16);
    *reinterpret_cast<uint4*>((char*)ws + WS_STREAM_B + chunk * CHUNK_BYTES
                              + seg * SEG_BYTES + lane * 16) = o;
}

// ---------------- main (MFMA path) ----------------
__global__ __launch_bounds__(THREADS, 2) void vq_main(
    const float* __restrict__ x,      // [64][64][32][32]
    const float* __restrict__ cb,     // [1024][64] fp32 (epilogue gather)
    const float* __restrict__ ws_f,   // stream + cbsq
    float* __restrict__ out,
    double* __restrict__ ws_sum)
{
    __shared__ __align__(16) char smem[49152];    // x-stage fp32 [64][130], then B dbuf 2x24KB
    __shared__ float cbsqh_s[K_CODES];
    __shared__ float redv[2][M_BLOCK];
    __shared__ int   redi[2][M_BLOCK];
    __shared__ int   kidx_s[M_BLOCK];

    const int tid  = threadIdx.x;
    const int blk  = blockIdx.x;
    const int tok0 = blk * M_BLOCK;
    const int b    = tok0 >> 10;
    const int hw0  = tok0 & 1023;

    const int w   = tid >> 6;      // wave 0..3
    const int ln  = tid & 63;
    const int wr  = w >> 1;        // wave row: tokens wr*64..
    const int wc  = w & 1;         // wave col: codes wc*32.. per chunk
    const int l31 = ln & 31;
    const int l5  = ln >> 5;

    // ---- stage x tile [c][token] fp32 + cbsq/2 table ----
    float* xs = reinterpret_cast<float*>(smem);   // [64][130]
    #pragma unroll
    for (int j = 0; j < 32; ++j) {
        int idx = j * 256 + tid;
        int c = idx >> 7, t = idx & 127;
        xs[c * 130 + t] = x[((b * C_DIM + c) << 10) + hw0 + t];
    }
    #pragma unroll
    for (int r = 0; r < 4; ++r) {
        int q = r * 256 + tid;
        cbsqh_s[q] = ws_f[WS_CBSQH_F + q];
    }
    __syncthreads();

    // ---- build A fragments (x split, positive): afrag[mt][term][s4] ----
    // A layout (32x32x16): row = l&31, k = (l>>5)*8 + j
    bf16x8 afrag[2][3][4];
    #pragma unroll
    for (int mt = 0; mt < 2; ++mt) {
        const int token = wr * 64 + mt * 32 + l31;
        #pragma unroll
        for (int s4 = 0; s4 < 4; ++s4) {
            const int cb0 = s4 * 16 + l5 * 8;
            #pragma unroll
            for (int j = 0; j < 8; ++j) {
                float v  = xs[(cb0 + j) * 130 + token];
                float h  = bf2f(f2bf(v));
                float r1 = v - h;                 // exact
                float m  = bf2f(f2bf(r1));
                float r2 = r1 - m;                // exact
                afrag[mt][0][s4][j] = (short)f2bf(h);
                afrag[mt][1][s4][j] = (short)f2bf(m);
                afrag[mt][2][s4][j] = (short)f2bf(r2);
            }
        }
    }
    __syncthreads();   // everyone done with xs before B staging overwrites it

    const char* stream = (const char*)ws_f + WS_STREAM_B;

    // stage chunk 0 into buf0 (linear dest: lane ln -> seg base + ln*16)
    {
        char* buf = smem;
        #pragma unroll
        for (int it = 0; it < 6; ++it) {
            int seg = w * 6 + it;
            const char* g = stream + 0 * CHUNK_BYTES + seg * SEG_BYTES + ln * 16;
            __builtin_amdgcn_global_load_lds((gv_t*)g, (lv_t*)(buf + seg * SEG_BYTES), 16, 0, 0);
        }
    }
    __syncthreads();

    float minv[2][16];
    int   mini[2][16];
    #pragma unroll
    for (int mt = 0; mt < 2; ++mt)
        #pragma unroll
        for (int r = 0; r < 16; ++r) { minv[mt][r] = 3.4e38f; mini[mt][r] = 0; }

    for (int ch = 0; ch < N_CHUNKS; ++ch) {
        // prefetch next chunk into the other buffer (drained by end-of-loop barrier)
        if (ch < N_CHUNKS - 1) {
            char* nbuf = smem + ((ch + 1) & 1) * CHUNK_BYTES;
            #pragma unroll
            for (int it = 0; it < 6; ++it) {
                int seg = w * 6 + it;
                const char* g = stream + (ch + 1) * CHUNK_BYTES + seg * SEG_BYTES + ln * 16;
                __builtin_amdgcn_global_load_lds((gv_t*)g, (lv_t*)(nbuf + seg * SEG_BYTES), 16, 0, 0);
            }
        }

        const char* bbase = smem + (ch & 1) * CHUNK_BYTES;
        const float h = cbsqh_s[ch * N_CHUNK + wc * 32 + l31];
        floatx16 acc0, acc1;
        #pragma unroll
        for (int r = 0; r < 16; ++r) { acc0[r] = h; acc1[r] = h; }

        #pragma unroll
        for (int tb = 0; tb < 3; ++tb) {
            #pragma unroll
            for (int s4 = 0; s4 < 4; ++s4) {
                bf16x8 bf = *reinterpret_cast<const bf16x8*>(
                    bbase + ((wc * 3 + tb) * 4 + s4) * SEG_BYTES + ln * 16);
                #pragma unroll
                for (int a = 0; a < 3; ++a) {     // pairs with a+tb<=2 (6 products)
                    if (a + tb <= 2) {
                        acc0 = __builtin_amdgcn_mfma_f32_32x32x16_bf16(afrag[0][a][s4], bf, acc0, 0, 0, 0);
                        acc1 = __builtin_amdgcn_mfma_f32_32x32x16_bf16(afrag[1][a][s4], bf, acc1, 0, 0, 0);
                    }
                }
            }
        }

        // score = 0.5|c|^2 - dot (in acc); running argmin, strict < keeps lowest chunk
        const int idxc = ch * N_CHUNK + wc * 32 + l31;
        #pragma unroll
        for (int r = 0; r < 16; ++r) {
            float s0 = acc0[r];
            if (s0 < minv[0][r]) { minv[0][r] = s0; mini[0][r] = idxc; }
            float s1 = acc1[r];
            if (s1 < minv[1][r]) { minv[1][r] = s1; mini[1][r] = idxc; }
        }
        __syncthreads();   // drains staged loads (vmcnt 0) + protects buffer swap
    }

    // ---- butterfly argmin across the 32 lanes of each column group ----
    #pragma unroll
    for (int off = 1; off < 32; off <<= 1) {
        #pragma unroll
        for (int mt = 0; mt < 2; ++mt)
            #pragma unroll
            for (int r = 0; r < 16; ++r) {
                float ov = __shfl_xor(minv[mt][r], off, 64);
                int   oi = __shfl_xor(mini[mt][r], off, 64);
                if (ov < minv[mt][r] || (ov == minv[mt][r] && oi < mini[mt][r])) {
                    minv[mt][r] = ov; mini[mt][r] = oi;
                }
            }
    }
    if (l31 == 0) {
        #pragma unroll
        for (int mt = 0; mt < 2; ++mt)
            #pragma unroll
            for (int r = 0; r < 16; ++r) {
                int row = (r & 3) + ((r >> 2) << 3) + (l5 << 2);  // verified 32x32 C/D map
                int token = wr * 64 + mt * 32 + row;
                redv[wc][token] = minv[mt][r];
                redi[wc][token] = mini[mt][r];
            }
    }
    __syncthreads();

    if (tid < M_BLOCK) {
        float v0 = redv[0][tid]; int i0 = redi[0][tid];
        float v1 = redv[1][tid]; int i1 = redi[1][tid];
        int bi = (v1 < v0 || (v1 == v0 && i1 < i0)) ? i1 : i0;
        kidx_s[tid] = bi;
        out[IDX_OFF + tok0 + tid] = (float)bi;
    }
    __syncthreads();

    // ---- epilogue: quant (STE form) + loss partial ----
    {
        const int i  = tid & (M_BLOCK - 1);
        const int c0 = tid >> 7;
        const int kk = kidx_s[i];
        const float* crow = cb + kk * C_DIM;      // L2-resident gather
        float lsum = 0.f;
        #pragma unroll
        for (int j = 0; j < 32; ++j) {
            int c = c0 * 32 + j;
            float q  = crow[c];
            float xv = x[((b * C_DIM + c) << 10) + hw0 + i];
            float d  = q - xv;                    // (quant - xt)
            lsum = fmaf(d, d, lsum);
            out[QUANT_OFF + ((b * C_DIM + c) << 10) + hw0 + i] = xv + d;  // xt + sg(q-x)
        }
        #pragma unroll
        for (int off = 32; off > 0; off >>= 1)
            lsum += __shfl_down(lsum, off, 64);
        if ((tid & 63) == 0)
            atomicAdd(ws_sum, (double)lsum);
    }
}

// ---------------- fallback (round-2-verified VALU path, used if ws too small) ----------------
#define CB_PAD 68
__global__ __launch_bounds__(THREADS, 2) void vq_main_valu(
    const float* __restrict__ x,
    const float* __restrict__ cb,
    float* __restrict__ out,
    double* __restrict__ ws_sum)
{
    __shared__ float xt_s[C_DIM][M_BLOCK];
    __shared__ float cb_s[C_DIM][CB_PAD];
    __shared__ float cbsq_all[K_CODES];
    __shared__ float red_v[8][M_BLOCK];
    __shared__ int   red_i[8][M_BLOCK];
    __shared__ int   kidx_s[M_BLOCK];

    const int tid  = threadIdx.x;
    const int tok0 = blockIdx.x * M_BLOCK;
    const int b_img = tok0 >> 10;
    const int hw0   = tok0 & 1023;

    #pragma unroll
    for (int r = 0; r < 4; ++r) {
        int k = tid + r * THREADS;
        const float4* row = reinterpret_cast<const float4*>(cb + k * C_DIM);
        float s = 0.f;
        #pragma unroll
        for (int j = 0; j < 16; ++j) {
            float4 v = row[j];
            s = fmaf(v.x, v.x, s); s = fmaf(v.y, v.y, s);
            s = fmaf(v.z, v.z, s); s = fmaf(v.w, v.w, s);
        }
        cbsq_all[k] = s;
    }
    {
        const int i  = tid & (M_BLOCK - 1);
        const int c0 = tid >> 7;
        #pragma unroll
        for (int j = 0; j < 32; ++j) {
            int c = c0 + 2 * j;
            xt_s[c][i] = x[((b_img * C_DIM + c) << 10) + hw0 + i];
        }
    }

    const int tl = tid & 31;
    const int kg = tid >> 5;
    float minv[4]; int mini[4];
    #pragma unroll
    for (int m = 0; m < 4; ++m) { minv[m] = 3.4e38f; mini[m] = 0; }

    for (int ch = 0; ch < 16; ++ch) {
        __syncthreads();
        for (int t = tid; t < 64 * C_DIM; t += THREADS) {
            int kl = t >> 6, c = t & 63;
            cb_s[c][kl] = cb[(ch * 64 + kl) * C_DIM + c];
        }
        __syncthreads();
        float dot[4][8];
        #pragma unroll
        for (int m = 0; m < 4; ++m)
            #pragma unroll
            for (int k = 0; k < 8; ++k) dot[m][k] = 0.f;
        #pragma unroll 4
        for (int c = 0; c < C_DIM; ++c) {
            float4 xv  = *reinterpret_cast<const float4*>(&xt_s[c][tl * 4]);
            float4 cv0 = *reinterpret_cast<const float4*>(&cb_s[c][kg * 8]);
            float4 cv1 = *reinterpret_cast<const float4*>(&cb_s[c][kg * 8 + 4]);
            float xa[4] = {xv.x, xv.y, xv.z, xv.w};
            float ca[8] = {cv0.x, cv0.y, cv0.z, cv0.w, cv1.x, cv1.y, cv1.z, cv1.w};
            #pragma unroll
            for (int m = 0; m < 4; ++m)
                #pragma unroll
                for (int k = 0; k < 8; ++k)
                    dot[m][k] = fmaf(xa[m], ca[k], dot[m][k]);
        }
        const int codebase = ch * 64 + kg * 8;
        #pragma unroll
        for (int k = 0; k < 8; ++k) {
            float csq = cbsq_all[codebase + k];
            #pragma unroll
            for (int m = 0; m < 4; ++m) {
                float sc = fmaf(-2.f, dot[m][k], csq);
                if (sc < minv[m]) { minv[m] = sc; mini[m] = codebase + k; }
            }
        }
    }
    #pragma unroll
    for (int m = 0; m < 4; ++m) {
        red_v[kg][tl * 4 + m] = minv[m];
        red_i[kg][tl * 4 + m] = mini[m];
    }
    __syncthreads();
    if (tid < M_BLOCK) {
        float bv = red_v[0][tid]; int bi = red_i[0][tid];
        #pragma unroll
        for (int g = 1; g < 8; ++g) {
            float v = red_v[g][tid]; int ii = red_i[g][tid];
            if (v < bv || (v == bv && ii < bi)) { bv = v; bi = ii; }
        }
        kidx_s[tid] = bi;
        out[IDX_OFF + tok0 + tid] = (float)bi;
    }
    __syncthreads();
    {
        const int i  = tid & (M_BLOCK - 1);
        const int c0 = tid >> 7;
        const int kk = kidx_s[i];
        const float* crow = cb + kk * C_DIM;
        float lsum = 0.f;
        #pragma unroll
        for (int j = 0; j < 32; ++j) {
            int c = c0 * 32 + j;
            float q  = crow[c];
            float xv = xt_s[c][i];
            float d  = q - xv;
            lsum = fmaf(d, d, lsum);
            out[QUANT_OFF + ((b_img * C_DIM + c) << 10) + hw0 + i] = xv + d;
        }
        #pragma unroll
        for (int off = 32; off > 0; off >>= 1)
            lsum += __shfl_down(lsum, off, 64);
        if ((tid & 63) == 0)
            atomicAdd(ws_sum, (double)lsum);
    }
}

__global__ void vq_finalize(const double* __restrict__ ws_sum,
                            float* __restrict__ out)
{
    float m = (float)(ws_sum[0] / 4194304.0);
    out[LOSS_OFF]     = m;   // loss_embed
    out[LOSS_OFF + 1] = m;   // loss_commitment (identical forward value)
}

extern "C" void kernel_launch(void* const* d_in, const int* in_sizes, int n_in,
                              void* d_out, int out_size, void* d_ws, size_t ws_size,
                              hipStream_t stream) {
    const float* x  = (const float*)d_in[0];
    const float* cb = (const float*)d_in[1];
    float* out      = (float*)d_out;

    hipMemsetAsync(d_ws, 0, sizeof(double), stream);
    if (ws_size >= (size_t)WS_NEEDED) {
        vq_prep<<<100, THREADS, 0, stream>>>(cb, (float*)d_ws);
        vq_main<<<512, THREADS, 0, stream>>>(x, cb, (const float*)d_ws, out, (double*)d_ws);
    } else {
        vq_main_valu<<<512, THREADS, 0, stream>>>(x, cb, out, (double*)d_ws);
    }
    vq_finalize<<<1, 1, 0, stream>>>((const double*)d_ws, out);
}